// Round 5
// baseline (330.718 us; speedup 1.0000x reference)
//
#include <hip/hip_runtime.h>
#include <stdint.h>

#define T_TOK 2048
#define D_DIM 1024
#define H_DIM 2048
#define N_EXP 8
#define MAXS  4608   // max padded slots: 4096 + 8*63 = 4600 -> 4608

// workspace layout (bytes)
#define WS_CNT    0
#define WS_BTOK   256
#define WS_BW     (WS_BTOK + N_EXP*2048*4)
#define WS_XG     (WS_BW + N_EXP*2048*4)        // 16B aligned
#define WS_HBUF   (WS_XG + (size_t)MAXS*1024*2)
#define WS_W1T    (WS_HBUF + (size_t)MAXS*2048*2)
#define WS_W2T    (WS_W1T + (size_t)N_EXP*1024*2048*2)

typedef __bf16 bf16x8 __attribute__((ext_vector_type(8)));
typedef float  f32x4  __attribute__((ext_vector_type(4)));

__device__ __forceinline__ unsigned short f2bf(float f) {
  unsigned int u = __float_as_uint(f);
  u += 0x7fffu + ((u >> 16) & 1u);   // round-to-nearest-even
  return (unsigned short)(u >> 16);
}

// fast tanh-approx gelu: tanh(u) = sign(u)*(1-e^{-2|u|})/(1+e^{-2|u|})
__device__ __forceinline__ float gelu_tanh(float x) {
  const float u = 0.7978845608028654f * (x + 0.044715f * x * x * x);
  const float t = __expf(-2.0f * fabsf(u));
  const float th = (1.0f - t) * __builtin_amdgcn_rcpf(1.0f + t);
  return 0.5f * x * (1.0f + copysignf(th, u));
}

// ---------------- device bodies ----------------

// 64x64 fp32->bf16 transpose tile. in: rows of Cin floats; out: rows of Rout bf16.
__device__ __forceinline__ void transpose_body(const float* __restrict__ in,
                                               unsigned short* __restrict__ out,
                                               int Rout, int Cin, int tx, int ty,
                                               void* smem_) {
  float (*tile)[68] = (float (*)[68])smem_;   // 64x68 fp32 = 17408 B
  const int c0 = tx * 64, r0 = ty * 64;
  const int tid = threadIdx.x;
#pragma unroll
  for (int p = 0; p < 4; ++p) {
    const int idx = p * 256 + tid;
    const int r = idx >> 4, c4 = idx & 15;
    *(float4*)&tile[r][c4 * 4] = *(const float4*)(in + (size_t)(r0 + r) * Cin + c0 + c4 * 4);
  }
  __syncthreads();
#pragma unroll
  for (int p = 0; p < 2; ++p) {
    const int idx = p * 256 + tid;
    const int oc = idx >> 3, seg = idx & 7;
    unsigned u[4];
#pragma unroll
    for (int j = 0; j < 4; ++j) {
      const unsigned lo = f2bf(tile[seg * 8 + 2 * j][oc]);
      const unsigned hi = f2bf(tile[seg * 8 + 2 * j + 1][oc]);
      u[j] = lo | (hi << 16);
    }
    *(uint4*)(out + (size_t)(c0 + oc) * Rout + r0 + seg * 8) = make_uint4(u[0], u[1], u[2], u[3]);
  }
}

// one wave per token: logits = x @ Wg + bg; top-2; softmax; bucket scatter
__device__ __forceinline__ void gate_body(int t, const float* __restrict__ x,
                                          const float* __restrict__ Wg,
                                          const float* __restrict__ bg,
                                          float* __restrict__ out_idx,
                                          int* __restrict__ cnt, int* __restrict__ btok,
                                          float* __restrict__ bw) {
  const int lane = threadIdx.x & 63;
  float p[8];
#pragma unroll
  for (int i = 0; i < 8; ++i) p[i] = 0.f;
  const float* xr = x + (size_t)t * D_DIM;
  for (int i = lane; i < D_DIM; i += 64) {
    const float xv = xr[i];
    const float4 wa = ((const float4*)(Wg + i * 8))[0];
    const float4 wb = ((const float4*)(Wg + i * 8))[1];
    p[0] += xv * wa.x; p[1] += xv * wa.y; p[2] += xv * wa.z; p[3] += xv * wa.w;
    p[4] += xv * wb.x; p[5] += xv * wb.y; p[6] += xv * wb.z; p[7] += xv * wb.w;
  }
#pragma unroll
  for (int off = 32; off > 0; off >>= 1) {
#pragma unroll
    for (int i = 0; i < 8; ++i) p[i] += __shfl_xor(p[i], off);
  }
  if (lane == 0) {
#pragma unroll
    for (int i = 0; i < 8; ++i) p[i] += bg[i];
    int i0 = 0; float v0 = p[0];
#pragma unroll
    for (int i = 1; i < 8; ++i) if (p[i] > v0) { v0 = p[i]; i0 = i; }
    int i1 = -1; float v1 = -3.4e38f;
#pragma unroll
    for (int i = 0; i < 8; ++i) if (i != i0 && p[i] > v1) { v1 = p[i]; i1 = i; }
    const float ex = expf(v1 - v0);
    const float inv = 1.f / (1.f + ex);
    out_idx[t * 2 + 0] = (float)i0;
    out_idx[t * 2 + 1] = (float)i1;
    int s0 = atomicAdd(&cnt[i0], 1);
    btok[i0 * 2048 + s0] = t; bw[i0 * 2048 + s0] = inv;
    int s1 = atomicAdd(&cnt[i1], 1);
    btok[i1 * 2048 + s1] = t; bw[i1 * 2048 + s1] = ex * inv;
  }
}

// inline padded prefix over the 8 expert counts
__device__ __forceinline__ void expert_seg(const int* __restrict__ cnt, int e,
                                           int& base, int& ce, int& pcnt, int& total) {
  int off = 0; base = 0; ce = 0; pcnt = 0;
#pragma unroll
  for (int i = 0; i < N_EXP; ++i) {
    const int c = cnt[i];
    const int p = (c + 63) & ~63;
    if (i == e) { base = off; ce = c; pcnt = p; }
    off += p;
  }
  total = off;
}

// MODE 0: Hbuf[s][n] = gelu(Xg[s] @ W1t[e]^T + b1[e])     (K=1024, N=2048, SK=1)
// MODE 1: out[tok]  += w_s * (Hbuf[s] @ W2t[e]^T + b2[e]) (K=2048, N=1024, SK=2, atomic)
// 64x128 tiles (4 waves 2x2, acc 2x4 each), double-buffered LDS, one barrier/iter.
// 64-row M tiles deliberately (not 128): with M~4600 total, 128-row tiles halve
// active blocks -> occupancy 37%->20% and gemm 63.6->70.9us (measured R1).
template <int MODE>
__device__ __forceinline__ void gemm_body(
    int lin, const unsigned short* __restrict__ A, const unsigned short* __restrict__ B,
    const float* __restrict__ bias, const int* __restrict__ cnt,
    const int* __restrict__ btok, const float* __restrict__ bw,
    unsigned short* __restrict__ Hout, float* __restrict__ out, void* smem_) {
  constexpr int K   = (MODE == 0) ? D_DIM : H_DIM;
  constexpr int SK  = (MODE == 0) ? 1 : 2;
  constexpr int KS  = K / SK;
  constexpr int NIT = KS / 32;

  const int glo = lin & 7;
  const int mt  = (lin >> 3) & 31;            // up to 32 m-tiles of 64 rows
  const int g   = ((lin >> 8) << 3) | glo;    // 0..127
  int nt, e, ksl;
  if (MODE == 0) { nt = g & 15; e = g >> 4; ksl = 0; }
  else           { nt = g & 7;  e = (g >> 3) & 7; ksl = g >> 6; }

  int base, ce, pcnt, total;
  expert_seg(cnt, e, base, ce, pcnt, total);
  if (mt * 64 >= pcnt) return;
  const int row0 = base + mt * 64;
  const int n0 = nt * 128;

  unsigned short (*As)[64 * 32] = (unsigned short (*)[64 * 32])smem_;              // 8 KB
  unsigned short (*Bs)[128 * 32] = (unsigned short (*)[128 * 32])((char*)smem_ + 8192);  // 16 KB

  const int tid = threadIdx.x;
  const int lane = tid & 63;
  const int wv = tid >> 6;
  const int wm = wv >> 1;
  const int wn = wv & 1;

  const unsigned short* Ab = A + (size_t)row0 * K + ksl * KS;
  const unsigned short* Bb = B + (size_t)e * ((size_t)H_DIM * D_DIM) + (size_t)n0 * K + ksl * KS;

  f32x4 acc[2][4];
#pragma unroll
  for (int i = 0; i < 2; ++i)
#pragma unroll
    for (int j = 0; j < 4; ++j) acc[i][j] = (f32x4)(0.0f);

  const int subr = lane >> 2;        // 0..15
  const int ks = (lane & 3) * 8;     // 0,8,16,24 halfs
  const int fr = lane & 15;
  const int kq = (lane >> 4) * 8;

  auto stage = [&](int kt, int b) {
    const int k0 = kt * 32;
    {  // A: 4 chunks of 16 rows, one per wave
      const int r = wv * 16 + subr;
      const unsigned short* ga = Ab + (size_t)r * K + (k0 + ks);
      __builtin_amdgcn_global_load_lds(
          (__attribute__((address_space(1))) void*)ga,
          (__attribute__((address_space(3))) void*)(As[b] + wv * 16 * 32), 16, 0, 0);
    }
#pragma unroll
    for (int it = 0; it < 2; ++it) {  // B: 8 chunks, two per wave
      const int ci = wv + it * 4;
      const int r = ci * 16 + subr;
      const unsigned short* gb = Bb + (size_t)r * K + (k0 + ks);
      __builtin_amdgcn_global_load_lds(
          (__attribute__((address_space(1))) void*)gb,
          (__attribute__((address_space(3))) void*)(Bs[b] + ci * 16 * 32), 16, 0, 0);
    }
  };

  stage(0, 0);
  for (int i = 0; i < NIT; ++i) {
    const int b = i & 1;
    __syncthreads();                  // drains prefetch into buf b; protects WAR on b^1
    if (i + 1 < NIT) stage(i + 1, b ^ 1);
    bf16x8 av[2], bv[4];
#pragma unroll
    for (int mi = 0; mi < 2; ++mi)
      av[mi] = *(const bf16x8*)(As[b] + (wm * 32 + mi * 16 + fr) * 32 + kq);
#pragma unroll
    for (int ni = 0; ni < 4; ++ni)
      bv[ni] = *(const bf16x8*)(Bs[b] + (wn * 64 + ni * 16 + fr) * 32 + kq);
#pragma unroll
    for (int mi = 0; mi < 2; ++mi)
#pragma unroll
      for (int ni = 0; ni < 4; ++ni)
        acc[mi][ni] = __builtin_amdgcn_mfma_f32_16x16x32_bf16(av[mi], bv[ni], acc[mi][ni], 0, 0, 0);
  }

  if (MODE == 0) {
    const float* bb = bias + (size_t)e * H_DIM + n0;
#pragma unroll
    for (int mi = 0; mi < 2; ++mi) {
      const int rb = wm * 32 + mi * 16 + (lane >> 4) * 4;
#pragma unroll
      for (int r = 0; r < 4; ++r) {
        unsigned short* hp = Hout + (size_t)(row0 + rb + r) * H_DIM + n0;
#pragma unroll
        for (int ni = 0; ni < 4; ++ni) {
          const int col = wn * 64 + ni * 16 + fr;
          hp[col] = f2bf(gelu_tanh(acc[mi][ni][r] + bb[col]));
        }
      }
    }
  } else {
    const float* bb = bias + (size_t)e * D_DIM + n0;
#pragma unroll
    for (int mi = 0; mi < 2; ++mi) {
      const int rb = wm * 32 + mi * 16 + (lane >> 4) * 4;
#pragma unroll
      for (int r = 0; r < 4; ++r) {
        const int local = mt * 64 + rb + r;
        if (local < ce) {
          const int tok = btok[e * 2048 + local];
          const float w = bw[e * 2048 + local];
          float* op = out + (size_t)tok * D_DIM + n0;
#pragma unroll
          for (int ni = 0; ni < 4; ++ni) {
            const int col = wn * 64 + ni * 16 + fr;
            const float bias_once = (ksl == 0) ? bb[col] : 0.f;
            atomicAdd(op + col, w * (acc[mi][ni][r] + bias_once));
          }
        }
      }
    }
  }
}

// ---------------- kernels ----------------

// blocks [0,2048): zero out; [2048,2560): gate (4 tok/blk).
// Both trivial-VGPR bodies -> safe to co-compile. cnt zeroed BEFORE via memset node.
// W1 transpose deliberately NOT fused here: R3 showed the branchy fusion compiled
// to VGPR=16, strangling the transpose's 4-deep float4 staging (81.5us vs <32us
// standalone, 983 GB/s vs >=3 TB/s).
__global__ void __launch_bounds__(256) gate_zero_kernel(
    const float* __restrict__ x, const float* __restrict__ Wg,
    const float* __restrict__ bg, float* __restrict__ out,
    int* __restrict__ cnt, int* __restrict__ btok, float* __restrict__ bw) {
  const int bid = blockIdx.x;
  if (bid < 2048) {
    ((float4*)out)[bid * 256 + threadIdx.x] = make_float4(0.f, 0.f, 0.f, 0.f);
  } else {
    gate_body((bid - 2048) * 4 + (threadIdx.x >> 6), x, Wg, bg,
              out + (size_t)T_TOK * D_DIM, cnt, btok, bw);
  }
}

// standalone W1 transpose (exact R0/R2-proven shape): W1 [e][1024][2048] -> W1t [e][2048][1024]
__global__ void __launch_bounds__(256) w1t_kernel(const float* __restrict__ W1,
                                                  unsigned short* __restrict__ W1t) {
  __shared__ __align__(16) char smem[17408];
  const int e = blockIdx.y;
  const int lin = blockIdx.x;   // 0..511: 32 tx x 16 ty
  transpose_body(W1 + (size_t)e * (D_DIM * H_DIM), W1t + (size_t)e * (D_DIM * H_DIM),
                 D_DIM, H_DIM, lin & 31, lin >> 5, smem);
}

// one block per padded slot row: gather routed token row fp32 -> bf16 (pad rows = 0)
__global__ void gather_cvt(const float* __restrict__ x, const int* __restrict__ cnt,
                           const int* __restrict__ btok, unsigned short* __restrict__ Xg) {
  const int s = blockIdx.x;
  int off = 0, e = -1, loc = 0, c_e = 0;
#pragma unroll
  for (int i = 0; i < N_EXP; ++i) {
    const int c = cnt[i];
    const int p = (c + 63) & ~63;
    if (e < 0 && s < off + p) { e = i; loc = s - off; c_e = c; }
    off += p;
  }
  if (e < 0) return;
  uint2* orow = (uint2*)(Xg + (size_t)s * D_DIM);
  if (loc < c_e) {
    const int t = btok[e * 2048 + loc];
    const float4 v = ((const float4*)(x + (size_t)t * D_DIM))[threadIdx.x];
    uint2 u;
    u.x = (unsigned)f2bf(v.x) | ((unsigned)f2bf(v.y) << 16);
    u.y = (unsigned)f2bf(v.z) | ((unsigned)f2bf(v.w) << 16);
    orow[threadIdx.x] = u;
  } else {
    orow[threadIdx.x] = make_uint2(0u, 0u);
  }
}

// blocks [0,4096): moe_gemm<0>; [4096,8192): W2 transpose (needed only by gemm1).
// This fusion WORKS (R3: combined <=81us vs 63.6 gemm0 alone): the gemm branch
// forces a healthy VGPR budget (44+) that the transpose branch inherits, and the
// memory-bound transpose hides in gemm0's idle BW (~25%) and wave slots (~37%).
__global__ void __launch_bounds__(256) gemm0_w2t(
    const unsigned short* __restrict__ Xg, const unsigned short* __restrict__ W1t,
    const float* __restrict__ b1, const int* __restrict__ cnt,
    const int* __restrict__ btok, const float* __restrict__ bw,
    unsigned short* __restrict__ Hbuf, const float* __restrict__ W2,
    unsigned short* __restrict__ W2t) {
  __shared__ __align__(16) char smem[24576];
  if (blockIdx.x < 4096) {
    gemm_body<0>(blockIdx.x, Xg, W1t, b1, cnt, btok, bw, Hbuf, nullptr, smem);
  } else {
    const int lin = blockIdx.x - 4096;   // 0..4095
    const int e = lin >> 9, l9 = lin & 511;
    // W2 [2048][1024] -> W2t [1024][2048]: Rout=2048, Cin=1024, 16 tx x 32 ty
    transpose_body(W2 + (size_t)e * (D_DIM * H_DIM), W2t + (size_t)e * (D_DIM * H_DIM),
                   H_DIM, D_DIM, l9 & 15, l9 >> 4, smem);
  }
}

__global__ void __launch_bounds__(256) moe_gemm1(
    const unsigned short* __restrict__ Hbuf, const unsigned short* __restrict__ W2t,
    const float* __restrict__ b2, const int* __restrict__ cnt,
    const int* __restrict__ btok, const float* __restrict__ bw,
    float* __restrict__ out) {
  __shared__ __align__(16) char smem[24576];
  gemm_body<1>(blockIdx.x, Hbuf, W2t, b2, cnt, btok, bw, nullptr, out, smem);
}

extern "C" void kernel_launch(void* const* d_in, const int* in_sizes, int n_in,
                              void* d_out, int out_size, void* d_ws, size_t ws_size,
                              hipStream_t stream) {
  const float* moe_inp = (const float*)d_in[0];
  const float* Wg = (const float*)d_in[1];
  const float* bg = (const float*)d_in[2];
  const float* W1 = (const float*)d_in[3];
  const float* b1 = (const float*)d_in[4];
  const float* W2 = (const float*)d_in[5];
  const float* b2 = (const float*)d_in[6];
  float* out = (float*)d_out;

  char* ws = (char*)d_ws;
  int* cnt  = (int*)(ws + WS_CNT);
  int* btok = (int*)(ws + WS_BTOK);
  float* bw = (float*)(ws + WS_BW);
  unsigned short* Xg   = (unsigned short*)(ws + WS_XG);
  unsigned short* Hbuf = (unsigned short*)(ws + WS_HBUF);
  unsigned short* W1t  = (unsigned short*)(ws + WS_W1T);
  unsigned short* W2t  = (unsigned short*)(ws + WS_W2T);

  hipMemsetAsync(cnt, 0, 256, stream);   // gate atomics need cnt=0 (capturable memset node)
  gate_zero_kernel<<<dim3(2560), dim3(256), 0, stream>>>(moe_inp, Wg, bg, out,
                                                         cnt, btok, bw);
  w1t_kernel<<<dim3(512, N_EXP), dim3(256), 0, stream>>>(W1, W1t);
  gather_cvt<<<dim3(MAXS), dim3(256), 0, stream>>>(moe_inp, cnt, btok, Xg);
  gemm0_w2t<<<dim3(8192), dim3(256), 0, stream>>>(Xg, W1t, b1, cnt, btok, bw,
                                                  Hbuf, W2, W2t);
  moe_gemm1<<<dim3(4096), dim3(256), 0, stream>>>(Hbuf, W2t, b2, cnt, btok, bw, out);
}

// Round 6
// 319.679 us; speedup vs baseline: 1.0345x; 1.0345x over previous
//
#include <hip/hip_runtime.h>
#include <stdint.h>

#define T_TOK 2048
#define D_DIM 1024
#define H_DIM 2048
#define N_EXP 8
#define MAXS  4608   // max padded slots: 4096 + 8*63 = 4600 -> 4608

// workspace layout (bytes)
#define WS_CNT    0
#define WS_BTOK   256
#define WS_BW     (WS_BTOK + N_EXP*2048*4)
#define WS_XG     (WS_BW + N_EXP*2048*4)        // (Xg slot kept for layout stability; unused)
#define WS_HBUF   (WS_XG + (size_t)MAXS*1024*2)
#define WS_W1T    (WS_HBUF + (size_t)MAXS*2048*2)
#define WS_W2T    (WS_W1T + (size_t)N_EXP*1024*2048*2)

typedef __bf16 bf16x8 __attribute__((ext_vector_type(8)));
typedef float  f32x4  __attribute__((ext_vector_type(4)));

__device__ __forceinline__ unsigned short f2bf(float f) {
  unsigned int u = __float_as_uint(f);
  u += 0x7fffu + ((u >> 16) & 1u);   // round-to-nearest-even
  return (unsigned short)(u >> 16);
}

// fast tanh-approx gelu: tanh(u) = sign(u)*(1-e^{-2|u|})/(1+e^{-2|u|})
__device__ __forceinline__ float gelu_tanh(float x) {
  const float u = 0.7978845608028654f * (x + 0.044715f * x * x * x);
  const float t = __expf(-2.0f * fabsf(u));
  const float th = (1.0f - t) * __builtin_amdgcn_rcpf(1.0f + t);
  return 0.5f * x * (1.0f + copysignf(th, u));
}

// ---------------- device bodies ----------------

// 64x64 fp32->bf16 transpose tile. in: rows of Cin floats; out: rows of Rout bf16.
// REG-BATCHED staging: all 4 float4 loads into named regs BEFORE any LDS write,
// and all 16 LDS reads before the 2 global stores. R3 showed that when this body
// is co-compiled with trivial branches the allocator went to VGPR=16 and
// serialized the loads (81.5us vs <32us standalone); explicit batching forces
// >=16 data VGPRs live -> 4-deep load pipeline survives any co-compilation.
__device__ __forceinline__ void transpose_body(const float* __restrict__ in,
                                               unsigned short* __restrict__ out,
                                               int Rout, int Cin, int tx, int ty,
                                               void* smem_) {
  float (*tile)[68] = (float (*)[68])smem_;   // 64x68 fp32 = 17408 B
  const int c0 = tx * 64, r0 = ty * 64;
  const int tid = threadIdx.x;
  float4 v[4];
#pragma unroll
  for (int p = 0; p < 4; ++p) {
    const int idx = p * 256 + tid;
    const int r = idx >> 4, c4 = idx & 15;
    v[p] = *(const float4*)(in + (size_t)(r0 + r) * Cin + c0 + c4 * 4);
  }
#pragma unroll
  for (int p = 0; p < 4; ++p) {
    const int idx = p * 256 + tid;
    const int r = idx >> 4, c4 = idx & 15;
    *(float4*)&tile[r][c4 * 4] = v[p];
  }
  __syncthreads();
  unsigned u[2][4];
#pragma unroll
  for (int p = 0; p < 2; ++p) {
    const int idx = p * 256 + tid;
    const int oc = idx >> 3, seg = idx & 7;
#pragma unroll
    for (int j = 0; j < 4; ++j) {
      const unsigned lo = f2bf(tile[seg * 8 + 2 * j][oc]);
      const unsigned hi = f2bf(tile[seg * 8 + 2 * j + 1][oc]);
      u[p][j] = lo | (hi << 16);
    }
  }
#pragma unroll
  for (int p = 0; p < 2; ++p) {
    const int idx = p * 256 + tid;
    const int oc = idx >> 3, seg = idx & 7;
    *(uint4*)(out + (size_t)(c0 + oc) * Rout + r0 + seg * 8) =
        make_uint4(u[p][0], u[p][1], u[p][2], u[p][3]);
  }
}

// one wave per token: logits = x @ Wg + bg; top-2; softmax; bucket scatter
__device__ __forceinline__ void gate_body(int t, const float* __restrict__ x,
                                          const float* __restrict__ Wg,
                                          const float* __restrict__ bg,
                                          float* __restrict__ out_idx,
                                          int* __restrict__ cnt, int* __restrict__ btok,
                                          float* __restrict__ bw) {
  const int lane = threadIdx.x & 63;
  float p[8];
#pragma unroll
  for (int i = 0; i < 8; ++i) p[i] = 0.f;
  const float* xr = x + (size_t)t * D_DIM;
  for (int i = lane; i < D_DIM; i += 64) {
    const float xv = xr[i];
    const float4 wa = ((const float4*)(Wg + i * 8))[0];
    const float4 wb = ((const float4*)(Wg + i * 8))[1];
    p[0] += xv * wa.x; p[1] += xv * wa.y; p[2] += xv * wa.z; p[3] += xv * wa.w;
    p[4] += xv * wb.x; p[5] += xv * wb.y; p[6] += xv * wb.z; p[7] += xv * wb.w;
  }
#pragma unroll
  for (int off = 32; off > 0; off >>= 1) {
#pragma unroll
    for (int i = 0; i < 8; ++i) p[i] += __shfl_xor(p[i], off);
  }
  if (lane == 0) {
#pragma unroll
    for (int i = 0; i < 8; ++i) p[i] += bg[i];
    int i0 = 0; float v0 = p[0];
#pragma unroll
    for (int i = 1; i < 8; ++i) if (p[i] > v0) { v0 = p[i]; i0 = i; }
    int i1 = -1; float v1 = -3.4e38f;
#pragma unroll
    for (int i = 0; i < 8; ++i) if (i != i0 && p[i] > v1) { v1 = p[i]; i1 = i; }
    const float ex = expf(v1 - v0);
    const float inv = 1.f / (1.f + ex);
    out_idx[t * 2 + 0] = (float)i0;
    out_idx[t * 2 + 1] = (float)i1;
    int s0 = atomicAdd(&cnt[i0], 1);
    btok[i0 * 2048 + s0] = t; bw[i0 * 2048 + s0] = inv;
    int s1 = atomicAdd(&cnt[i1], 1);
    btok[i1 * 2048 + s1] = t; bw[i1 * 2048 + s1] = ex * inv;
  }
}

// inline padded prefix over the 8 expert counts
__device__ __forceinline__ void expert_seg(const int* __restrict__ cnt, int e,
                                           int& base, int& ce, int& pcnt, int& total) {
  int off = 0; base = 0; ce = 0; pcnt = 0;
#pragma unroll
  for (int i = 0; i < N_EXP; ++i) {
    const int c = cnt[i];
    const int p = (c + 63) & ~63;
    if (i == e) { base = off; ce = c; pcnt = p; }
    off += p;
  }
  total = off;
}

// MODE 0: Hbuf[s][n] = gelu(x[btok] @ W1t[e]^T + b1[e])   (K=1024, N=2048, SK=1)
//         A is reg-gathered DIRECTLY from x via btok (gather_cvt node eliminated):
//         each lane's slot row is fixed for the whole K loop; per K-step it loads
//         2x float4 (issue-early), packs to bf16 and ds_writes AFTER the MFMAs
//         (write-late) so HBM latency hides under compute.
// MODE 1: out[tok] += w_s * (Hbuf[s] @ W2t[e]^T + b2[e])  (K=2048, N=1024, SK=2, atomic)
// 64x128 tiles (4 waves 2x2, acc 2x4 each), double-buffered LDS, one barrier/iter.
// 64-row M tiles deliberately (not 128): with M~4600 total, 128-row tiles halve
// active blocks -> occupancy 37%->20% and gemm 63.6->70.9us (measured R1).
template <int MODE>
__device__ __forceinline__ void gemm_body(
    int lin, const float* __restrict__ X, const unsigned short* __restrict__ A,
    const unsigned short* __restrict__ B,
    const float* __restrict__ bias, const int* __restrict__ cnt,
    const int* __restrict__ btok, const float* __restrict__ bw,
    unsigned short* __restrict__ Hout, float* __restrict__ out, void* smem_) {
  constexpr int K   = (MODE == 0) ? D_DIM : H_DIM;
  constexpr int SK  = (MODE == 0) ? 1 : 2;
  constexpr int KS  = K / SK;
  constexpr int NIT = KS / 32;

  const int glo = lin & 7;
  const int mt  = (lin >> 3) & 31;            // up to 32 m-tiles of 64 rows
  const int g   = ((lin >> 8) << 3) | glo;    // 0..127
  int nt, e, ksl;
  if (MODE == 0) { nt = g & 15; e = g >> 4; ksl = 0; }
  else           { nt = g & 7;  e = (g >> 3) & 7; ksl = g >> 6; }

  int base, ce, pcnt, total;
  expert_seg(cnt, e, base, ce, pcnt, total);
  if (mt * 64 >= pcnt) return;
  const int row0 = base + mt * 64;
  const int n0 = nt * 128;

  unsigned short (*As)[64 * 32] = (unsigned short (*)[64 * 32])smem_;                    // 8 KB
  unsigned short (*Bs)[128 * 32] = (unsigned short (*)[128 * 32])((char*)smem_ + 8192);  // 16 KB

  const int tid = threadIdx.x;
  const int lane = tid & 63;
  const int wv = tid >> 6;
  const int wm = wv >> 1;
  const int wn = wv & 1;

  const unsigned short* Bb = B + (size_t)e * ((size_t)H_DIM * D_DIM) + (size_t)n0 * K + ksl * KS;

  f32x4 acc[2][4];
#pragma unroll
  for (int i = 0; i < 2; ++i)
#pragma unroll
    for (int j = 0; j < 4; ++j) acc[i][j] = (f32x4)(0.0f);

  const int subr = lane >> 2;        // 0..15
  const int ksf = (lane & 3) * 8;    // col offset in elems (8 per lane)
  const int fr = lane & 15;
  const int kq = (lane >> 4) * 8;

  // A-source setup
  const unsigned short* Ab = nullptr;   // MODE1
  const float* a_src = nullptr;         // MODE0
  bool a_real = false;
  if constexpr (MODE == 0) {
    const int al = mt * 64 + wv * 16 + subr;     // local slot row this lane stages
    a_real = (al < ce);
    const int tok = a_real ? btok[e * 2048 + al] : 0;
    a_src = X + (size_t)tok * D_DIM + ksf;
  } else {
    Ab = A + (size_t)row0 * K + ksl * KS;
  }

  float4 pa0, pa1;   // MODE0 A prefetch registers
  auto stageA_load = [&](int kt) {
    if constexpr (MODE == 0) {
      if (a_real) {
        pa0 = *(const float4*)(a_src + kt * 32);
        pa1 = *(const float4*)(a_src + kt * 32 + 4);
      } else {
        pa0 = make_float4(0.f, 0.f, 0.f, 0.f);
        pa1 = make_float4(0.f, 0.f, 0.f, 0.f);
      }
    }
  };
  auto stageA_write = [&](int b) {
    if constexpr (MODE == 0) {
      uint4 u;
      u.x = (unsigned)f2bf(pa0.x) | ((unsigned)f2bf(pa0.y) << 16);
      u.y = (unsigned)f2bf(pa0.z) | ((unsigned)f2bf(pa0.w) << 16);
      u.z = (unsigned)f2bf(pa1.x) | ((unsigned)f2bf(pa1.y) << 16);
      u.w = (unsigned)f2bf(pa1.z) | ((unsigned)f2bf(pa1.w) << 16);
      *(uint4*)(As[b] + (wv * 16 + subr) * 32 + ksf) = u;
    }
  };
  auto stage = [&](int kt, int b) {
    const int k0 = kt * 32;
    if constexpr (MODE == 1) {   // A: 4 chunks of 16 rows, one per wave (LDS-DMA)
      const int r = wv * 16 + subr;
      const unsigned short* ga = Ab + (size_t)r * K + (k0 + ksf);
      __builtin_amdgcn_global_load_lds(
          (__attribute__((address_space(1))) void*)ga,
          (__attribute__((address_space(3))) void*)(As[b] + wv * 16 * 32), 16, 0, 0);
    }
#pragma unroll
    for (int it = 0; it < 2; ++it) {  // B: 8 chunks, two per wave (LDS-DMA)
      const int ci = wv + it * 4;
      const int r = ci * 16 + subr;
      const unsigned short* gb = Bb + (size_t)r * K + (k0 + ksf);
      __builtin_amdgcn_global_load_lds(
          (__attribute__((address_space(1))) void*)gb,
          (__attribute__((address_space(3))) void*)(Bs[b] + ci * 16 * 32), 16, 0, 0);
    }
  };

  stageA_load(0);
  stage(0, 0);
  stageA_write(0);
  for (int i = 0; i < NIT; ++i) {
    const int b = i & 1;
    __syncthreads();                  // drains prefetch into buf b; protects WAR on b^1
    if (i + 1 < NIT) { stageA_load(i + 1); stage(i + 1, b ^ 1); }
    bf16x8 av[2], bv[4];
#pragma unroll
    for (int mi = 0; mi < 2; ++mi)
      av[mi] = *(const bf16x8*)(As[b] + (wm * 32 + mi * 16 + fr) * 32 + kq);
#pragma unroll
    for (int ni = 0; ni < 4; ++ni)
      bv[ni] = *(const bf16x8*)(Bs[b] + (wn * 64 + ni * 16 + fr) * 32 + kq);
#pragma unroll
    for (int mi = 0; mi < 2; ++mi)
#pragma unroll
      for (int ni = 0; ni < 4; ++ni)
        acc[mi][ni] = __builtin_amdgcn_mfma_f32_16x16x32_bf16(av[mi], bv[ni], acc[mi][ni], 0, 0, 0);
    if (i + 1 < NIT) stageA_write(b ^ 1);   // write-late: vmcnt wait hidden under MFMAs
  }

  if (MODE == 0) {
    const float* bb = bias + (size_t)e * H_DIM + n0;
#pragma unroll
    for (int mi = 0; mi < 2; ++mi) {
      const int rb = wm * 32 + mi * 16 + (lane >> 4) * 4;
#pragma unroll
      for (int r = 0; r < 4; ++r) {
        unsigned short* hp = Hout + (size_t)(row0 + rb + r) * H_DIM + n0;
#pragma unroll
        for (int ni = 0; ni < 4; ++ni) {
          const int col = wn * 64 + ni * 16 + fr;
          hp[col] = f2bf(gelu_tanh(acc[mi][ni][r] + bb[col]));
        }
      }
    }
  } else {
    const float* bb = bias + (size_t)e * D_DIM + n0;
#pragma unroll
    for (int mi = 0; mi < 2; ++mi) {
      const int rb = wm * 32 + mi * 16 + (lane >> 4) * 4;
#pragma unroll
      for (int r = 0; r < 4; ++r) {
        const int local = mt * 64 + rb + r;
        if (local < ce) {
          const int tok = btok[e * 2048 + local];
          const float w = bw[e * 2048 + local];
          float* op = out + (size_t)tok * D_DIM + n0;
#pragma unroll
          for (int ni = 0; ni < 4; ++ni) {
            const int col = wn * 64 + ni * 16 + fr;
            const float bias_once = (ksl == 0) ? bb[col] : 0.f;
            atomicAdd(op + col, w * (acc[mi][ni][r] + bias_once));
          }
        }
      }
    }
  }
}

// ---------------- kernels ----------------

// blocks [0,2048): zero out; [2048,2560): gate (4 tok/blk); [2560,6656): W1 transpose.
// cnt zeroed BEFORE via memset node (no intra-grid ordering). Transpose is now
// reg-batched (see transpose_body) so the R3 VGPR=16 strangulation cannot recur.
__global__ void __launch_bounds__(256) prep_kernel(
    const float* __restrict__ x, const float* __restrict__ Wg,
    const float* __restrict__ bg, const float* __restrict__ W1,
    float* __restrict__ out, int* __restrict__ cnt, int* __restrict__ btok,
    float* __restrict__ bw, unsigned short* __restrict__ W1t) {
  __shared__ __align__(16) char smem[17408];
  const int bid = blockIdx.x;
  if (bid < 2048) {
    ((float4*)out)[bid * 256 + threadIdx.x] = make_float4(0.f, 0.f, 0.f, 0.f);
  } else if (bid < 2560) {
    gate_body((bid - 2048) * 4 + (threadIdx.x >> 6), x, Wg, bg,
              out + (size_t)T_TOK * D_DIM, cnt, btok, bw);
  } else {
    const int lin = bid - 2560;          // 0..4095
    const int e = lin >> 9, l9 = lin & 511;
    // W1 [1024][2048] -> W1t [2048][1024]: out-stride 1024, 32 tx x 16 ty
    transpose_body(W1 + (size_t)e * (D_DIM * H_DIM), W1t + (size_t)e * (D_DIM * H_DIM),
                   D_DIM, H_DIM, l9 & 31, l9 >> 5, smem);
  }
}

// blocks [0,4096): moe_gemm<0> (A direct-gathered from x); [4096,8192): W2 transpose.
// W2t fusion proven in R3/R5 (combined 67us vs 63.6 bare gemm0): the gemm branch
// forces a healthy VGPR budget and the memory-bound transpose hides in gemm0's
// idle BW (~30%) and wave slots.
__global__ void __launch_bounds__(256) gemm0_w2t(
    const float* __restrict__ x, const unsigned short* __restrict__ W1t,
    const float* __restrict__ b1, const int* __restrict__ cnt,
    const int* __restrict__ btok, const float* __restrict__ bw,
    unsigned short* __restrict__ Hbuf, const float* __restrict__ W2,
    unsigned short* __restrict__ W2t) {
  __shared__ __align__(16) char smem[24576];
  if (blockIdx.x < 4096) {
    gemm_body<0>(blockIdx.x, x, nullptr, W1t, b1, cnt, btok, bw, Hbuf, nullptr, smem);
  } else {
    const int lin = blockIdx.x - 4096;   // 0..4095
    const int e = lin >> 9, l9 = lin & 511;
    // W2 [2048][1024] -> W2t [1024][2048]: out-stride 2048, 16 tx x 32 ty
    transpose_body(W2 + (size_t)e * (D_DIM * H_DIM), W2t + (size_t)e * (D_DIM * H_DIM),
                   H_DIM, D_DIM, l9 & 15, l9 >> 4, smem);
  }
}

__global__ void __launch_bounds__(256) moe_gemm1(
    const unsigned short* __restrict__ Hbuf, const unsigned short* __restrict__ W2t,
    const float* __restrict__ b2, const int* __restrict__ cnt,
    const int* __restrict__ btok, const float* __restrict__ bw,
    float* __restrict__ out) {
  __shared__ __align__(16) char smem[24576];
  gemm_body<1>(blockIdx.x, nullptr, Hbuf, W2t, b2, cnt, btok, bw, nullptr, out, smem);
}

extern "C" void kernel_launch(void* const* d_in, const int* in_sizes, int n_in,
                              void* d_out, int out_size, void* d_ws, size_t ws_size,
                              hipStream_t stream) {
  const float* moe_inp = (const float*)d_in[0];
  const float* Wg = (const float*)d_in[1];
  const float* bg = (const float*)d_in[2];
  const float* W1 = (const float*)d_in[3];
  const float* b1 = (const float*)d_in[4];
  const float* W2 = (const float*)d_in[5];
  const float* b2 = (const float*)d_in[6];
  float* out = (float*)d_out;

  char* ws = (char*)d_ws;
  int* cnt  = (int*)(ws + WS_CNT);
  int* btok = (int*)(ws + WS_BTOK);
  float* bw = (float*)(ws + WS_BW);
  unsigned short* Hbuf = (unsigned short*)(ws + WS_HBUF);
  unsigned short* W1t  = (unsigned short*)(ws + WS_W1T);
  unsigned short* W2t  = (unsigned short*)(ws + WS_W2T);

  hipMemsetAsync(cnt, 0, 256, stream);   // gate atomics need cnt=0 (capturable memset node)
  prep_kernel<<<dim3(6656), dim3(256), 0, stream>>>(moe_inp, Wg, bg, W1,
                                                    out, cnt, btok, bw, W1t);
  gemm0_w2t<<<dim3(8192), dim3(256), 0, stream>>>(moe_inp, W1t, b1, cnt, btok, bw,
                                                  Hbuf, W2, W2t);
  moe_gemm1<<<dim3(4096), dim3(256), 0, stream>>>(Hbuf, W2t, b2, cnt, btok, bw, out);
}

// Round 7
// 317.934 us; speedup vs baseline: 1.0402x; 1.0055x over previous
//
#include <hip/hip_runtime.h>
#include <stdint.h>

#define T_TOK 2048
#define D_DIM 1024
#define H_DIM 2048
#define N_EXP 8
#define MAXS  4608   // max padded slots: 4096 + 8*63 = 4600 -> 4608

// workspace layout (bytes)
#define WS_CNT    0
#define WS_BTOK   256
#define WS_BW     (WS_BTOK + N_EXP*2048*4)
#define WS_XG     (WS_BW + N_EXP*2048*4)        // (Xg slot kept for layout stability; unused)
#define WS_HBUF   (WS_XG + (size_t)MAXS*1024*2)
#define WS_W1T    (WS_HBUF + (size_t)MAXS*2048*2)
#define WS_W2T    (WS_W1T + (size_t)N_EXP*1024*2048*2)

typedef __bf16 bf16x8 __attribute__((ext_vector_type(8)));
typedef float  f32x4  __attribute__((ext_vector_type(4)));

__device__ __forceinline__ unsigned short f2bf(float f) {
  unsigned int u = __float_as_uint(f);
  u += 0x7fffu + ((u >> 16) & 1u);   // round-to-nearest-even
  return (unsigned short)(u >> 16);
}

// fast tanh-approx gelu: tanh(u) = sign(u)*(1-e^{-2|u|})/(1+e^{-2|u|})
__device__ __forceinline__ float gelu_tanh(float x) {
  const float u = 0.7978845608028654f * (x + 0.044715f * x * x * x);
  const float t = __expf(-2.0f * fabsf(u));
  const float th = (1.0f - t) * __builtin_amdgcn_rcpf(1.0f + t);
  return 0.5f * x * (1.0f + copysignf(th, u));
}

// ---------------- device bodies ----------------

// 64x64 fp32->bf16 transpose tile. in: rows of Cin floats; out: rows of Rout bf16.
// SCHED_BARRIER-FENCED staging: R3/R6 showed that when co-compiled with trivial
// branches, the scheduler sinks each global load next to its LDS write (VGPR=16/20,
// serial ~500cy round trips, 81us @ 1TB/s vs <35us standalone). C++-level reg
// batching (R6) did NOT stop it. sched_barrier(0) makes the reorder ILLEGAL:
// all 4 global_load_dwordx4 must issue before any ds_write -> 16 data VGPRs live,
// 4-deep load pipeline survives any co-compilation.
__device__ __forceinline__ void transpose_body(const float* __restrict__ in,
                                               unsigned short* __restrict__ out,
                                               int Rout, int Cin, int tx, int ty,
                                               void* smem_) {
  float (*tile)[68] = (float (*)[68])smem_;   // 64x68 fp32 = 17408 B
  const int c0 = tx * 64, r0 = ty * 64;
  const int tid = threadIdx.x;
  float4 v[4];
#pragma unroll
  for (int p = 0; p < 4; ++p) {
    const int idx = p * 256 + tid;
    const int r = idx >> 4, c4 = idx & 15;
    v[p] = *(const float4*)(in + (size_t)(r0 + r) * Cin + c0 + c4 * 4);
  }
  __builtin_amdgcn_sched_barrier(0);   // all 4 loads issue before any LDS write
#pragma unroll
  for (int p = 0; p < 4; ++p) {
    const int idx = p * 256 + tid;
    const int r = idx >> 4, c4 = idx & 15;
    *(float4*)&tile[r][c4 * 4] = v[p];
  }
  __syncthreads();
  unsigned u[2][4];
#pragma unroll
  for (int p = 0; p < 2; ++p) {
    const int idx = p * 256 + tid;
    const int oc = idx >> 3, seg = idx & 7;
#pragma unroll
    for (int j = 0; j < 4; ++j) {
      const unsigned lo = f2bf(tile[seg * 8 + 2 * j][oc]);
      const unsigned hi = f2bf(tile[seg * 8 + 2 * j + 1][oc]);
      u[p][j] = lo | (hi << 16);
    }
  }
  __builtin_amdgcn_sched_barrier(0);   // batch all LDS reads before the 2 stores
#pragma unroll
  for (int p = 0; p < 2; ++p) {
    const int idx = p * 256 + tid;
    const int oc = idx >> 3, seg = idx & 7;
    *(uint4*)(out + (size_t)(c0 + oc) * Rout + r0 + seg * 8) =
        make_uint4(u[p][0], u[p][1], u[p][2], u[p][3]);
  }
}

// one wave per token: logits = x @ Wg + bg; top-2; softmax; bucket scatter
__device__ __forceinline__ void gate_body(int t, const float* __restrict__ x,
                                          const float* __restrict__ Wg,
                                          const float* __restrict__ bg,
                                          float* __restrict__ out_idx,
                                          int* __restrict__ cnt, int* __restrict__ btok,
                                          float* __restrict__ bw) {
  const int lane = threadIdx.x & 63;
  float p[8];
#pragma unroll
  for (int i = 0; i < 8; ++i) p[i] = 0.f;
  const float* xr = x + (size_t)t * D_DIM;
  for (int i = lane; i < D_DIM; i += 64) {
    const float xv = xr[i];
    const float4 wa = ((const float4*)(Wg + i * 8))[0];
    const float4 wb = ((const float4*)(Wg + i * 8))[1];
    p[0] += xv * wa.x; p[1] += xv * wa.y; p[2] += xv * wa.z; p[3] += xv * wa.w;
    p[4] += xv * wb.x; p[5] += xv * wb.y; p[6] += xv * wb.z; p[7] += xv * wb.w;
  }
#pragma unroll
  for (int off = 32; off > 0; off >>= 1) {
#pragma unroll
    for (int i = 0; i < 8; ++i) p[i] += __shfl_xor(p[i], off);
  }
  if (lane == 0) {
#pragma unroll
    for (int i = 0; i < 8; ++i) p[i] += bg[i];
    int i0 = 0; float v0 = p[0];
#pragma unroll
    for (int i = 1; i < 8; ++i) if (p[i] > v0) { v0 = p[i]; i0 = i; }
    int i1 = -1; float v1 = -3.4e38f;
#pragma unroll
    for (int i = 0; i < 8; ++i) if (i != i0 && p[i] > v1) { v1 = p[i]; i1 = i; }
    const float ex = expf(v1 - v0);
    const float inv = 1.f / (1.f + ex);
    out_idx[t * 2 + 0] = (float)i0;
    out_idx[t * 2 + 1] = (float)i1;
    int s0 = atomicAdd(&cnt[i0], 1);
    btok[i0 * 2048 + s0] = t; bw[i0 * 2048 + s0] = inv;
    int s1 = atomicAdd(&cnt[i1], 1);
    btok[i1 * 2048 + s1] = t; bw[i1 * 2048 + s1] = ex * inv;
  }
}

// inline padded prefix over the 8 expert counts
__device__ __forceinline__ void expert_seg(const int* __restrict__ cnt, int e,
                                           int& base, int& ce, int& pcnt, int& total) {
  int off = 0; base = 0; ce = 0; pcnt = 0;
#pragma unroll
  for (int i = 0; i < N_EXP; ++i) {
    const int c = cnt[i];
    const int p = (c + 63) & ~63;
    if (i == e) { base = off; ce = c; pcnt = p; }
    off += p;
  }
  total = off;
}

// MODE 0: Hbuf[s][n] = gelu(x[btok] @ W1t[e]^T + b1[e])   (K=1024, N=2048, SK=1)
//         A reg-gathered directly from x via btok (no gather_cvt node).
// MODE 1: out[tok] += w_s * (Hbuf[s] @ W2t[e]^T + b2[e])  (K=2048, N=1024, SK=2, atomic)
// 64x128 tiles (4 waves 2x2, acc 2x4 each), double-buffered LDS, one barrier/iter.
// 64-row M tiles deliberately (not 128): with M~4600 total, 128-row tiles halve
// active blocks -> occupancy 37%->20% and gemm 63.6->70.9us (measured R1).
template <int MODE>
__device__ __forceinline__ void gemm_body(
    int lin, const float* __restrict__ X, const unsigned short* __restrict__ A,
    const unsigned short* __restrict__ B,
    const float* __restrict__ bias, const int* __restrict__ cnt,
    const int* __restrict__ btok, const float* __restrict__ bw,
    unsigned short* __restrict__ Hout, float* __restrict__ out, void* smem_) {
  constexpr int K   = (MODE == 0) ? D_DIM : H_DIM;
  constexpr int SK  = (MODE == 0) ? 1 : 2;
  constexpr int KS  = K / SK;
  constexpr int NIT = KS / 32;

  const int glo = lin & 7;
  const int mt  = (lin >> 3) & 31;            // up to 32 m-tiles of 64 rows
  const int g   = ((lin >> 8) << 3) | glo;    // 0..127
  int nt, e, ksl;
  if (MODE == 0) { nt = g & 15; e = g >> 4; ksl = 0; }
  else           { nt = g & 7;  e = (g >> 3) & 7; ksl = g >> 6; }

  int base, ce, pcnt, total;
  expert_seg(cnt, e, base, ce, pcnt, total);
  if (mt * 64 >= pcnt) return;
  const int row0 = base + mt * 64;
  const int n0 = nt * 128;

  unsigned short (*As)[64 * 32] = (unsigned short (*)[64 * 32])smem_;                    // 8 KB
  unsigned short (*Bs)[128 * 32] = (unsigned short (*)[128 * 32])((char*)smem_ + 8192);  // 16 KB

  const int tid = threadIdx.x;
  const int lane = tid & 63;
  const int wv = tid >> 6;
  const int wm = wv >> 1;
  const int wn = wv & 1;

  const unsigned short* Bb = B + (size_t)e * ((size_t)H_DIM * D_DIM) + (size_t)n0 * K + ksl * KS;

  f32x4 acc[2][4];
#pragma unroll
  for (int i = 0; i < 2; ++i)
#pragma unroll
    for (int j = 0; j < 4; ++j) acc[i][j] = (f32x4)(0.0f);

  const int subr = lane >> 2;        // 0..15
  const int ksf = (lane & 3) * 8;    // col offset in elems (8 per lane)
  const int fr = lane & 15;
  const int kq = (lane >> 4) * 8;

  // A-source setup
  const unsigned short* Ab = nullptr;   // MODE1
  const float* a_src = nullptr;         // MODE0
  bool a_real = false;
  if constexpr (MODE == 0) {
    const int al = mt * 64 + wv * 16 + subr;     // local slot row this lane stages
    a_real = (al < ce);
    const int tok = a_real ? btok[e * 2048 + al] : 0;
    a_src = X + (size_t)tok * D_DIM + ksf;
  } else {
    Ab = A + (size_t)row0 * K + ksl * KS;
  }

  float4 pa0, pa1;   // MODE0 A prefetch registers
  auto stageA_load = [&](int kt) {
    if constexpr (MODE == 0) {
      if (a_real) {
        pa0 = *(const float4*)(a_src + kt * 32);
        pa1 = *(const float4*)(a_src + kt * 32 + 4);
      } else {
        pa0 = make_float4(0.f, 0.f, 0.f, 0.f);
        pa1 = make_float4(0.f, 0.f, 0.f, 0.f);
      }
    }
  };
  auto stageA_write = [&](int b) {
    if constexpr (MODE == 0) {
      uint4 u;
      u.x = (unsigned)f2bf(pa0.x) | ((unsigned)f2bf(pa0.y) << 16);
      u.y = (unsigned)f2bf(pa0.z) | ((unsigned)f2bf(pa0.w) << 16);
      u.z = (unsigned)f2bf(pa1.x) | ((unsigned)f2bf(pa1.y) << 16);
      u.w = (unsigned)f2bf(pa1.z) | ((unsigned)f2bf(pa1.w) << 16);
      *(uint4*)(As[b] + (wv * 16 + subr) * 32 + ksf) = u;
    }
  };
  auto stage = [&](int kt, int b) {
    const int k0 = kt * 32;
    if constexpr (MODE == 1) {   // A: 4 chunks of 16 rows, one per wave (LDS-DMA)
      const int r = wv * 16 + subr;
      const unsigned short* ga = Ab + (size_t)r * K + (k0 + ksf);
      __builtin_amdgcn_global_load_lds(
          (__attribute__((address_space(1))) void*)ga,
          (__attribute__((address_space(3))) void*)(As[b] + wv * 16 * 32), 16, 0, 0);
    }
#pragma unroll
    for (int it = 0; it < 2; ++it) {  // B: 8 chunks, two per wave (LDS-DMA)
      const int ci = wv + it * 4;
      const int r = ci * 16 + subr;
      const unsigned short* gb = Bb + (size_t)r * K + (k0 + ksf);
      __builtin_amdgcn_global_load_lds(
          (__attribute__((address_space(1))) void*)gb,
          (__attribute__((address_space(3))) void*)(Bs[b] + ci * 16 * 32), 16, 0, 0);
    }
  };

  stageA_load(0);
  stage(0, 0);
  stageA_write(0);
  for (int i = 0; i < NIT; ++i) {
    const int b = i & 1;
    __syncthreads();                  // drains prefetch into buf b; protects WAR on b^1
    if (i + 1 < NIT) { stageA_load(i + 1); stage(i + 1, b ^ 1); }
    bf16x8 av[2], bv[4];
#pragma unroll
    for (int mi = 0; mi < 2; ++mi)
      av[mi] = *(const bf16x8*)(As[b] + (wm * 32 + mi * 16 + fr) * 32 + kq);
#pragma unroll
    for (int ni = 0; ni < 4; ++ni)
      bv[ni] = *(const bf16x8*)(Bs[b] + (wn * 64 + ni * 16 + fr) * 32 + kq);
#pragma unroll
    for (int mi = 0; mi < 2; ++mi)
#pragma unroll
      for (int ni = 0; ni < 4; ++ni)
        acc[mi][ni] = __builtin_amdgcn_mfma_f32_16x16x32_bf16(av[mi], bv[ni], acc[mi][ni], 0, 0, 0);
    if (i + 1 < NIT) stageA_write(b ^ 1);   // write-late: vmcnt wait hidden under MFMAs
  }

  if (MODE == 0) {
    const float* bb = bias + (size_t)e * H_DIM + n0;
#pragma unroll
    for (int mi = 0; mi < 2; ++mi) {
      const int rb = wm * 32 + mi * 16 + (lane >> 4) * 4;
#pragma unroll
      for (int r = 0; r < 4; ++r) {
        unsigned short* hp = Hout + (size_t)(row0 + rb + r) * H_DIM + n0;
#pragma unroll
        for (int ni = 0; ni < 4; ++ni) {
          const int col = wn * 64 + ni * 16 + fr;
          hp[col] = f2bf(gelu_tanh(acc[mi][ni][r] + bb[col]));
        }
      }
    }
  } else {
    const float* bb = bias + (size_t)e * D_DIM + n0;
#pragma unroll
    for (int mi = 0; mi < 2; ++mi) {
      const int rb = wm * 32 + mi * 16 + (lane >> 4) * 4;
#pragma unroll
      for (int r = 0; r < 4; ++r) {
        const int local = mt * 64 + rb + r;
        if (local < ce) {
          const int tok = btok[e * 2048 + local];
          const float w = bw[e * 2048 + local];
          float* op = out + (size_t)tok * D_DIM + n0;
#pragma unroll
          for (int ni = 0; ni < 4; ++ni) {
            const int col = wn * 64 + ni * 16 + fr;
            const float bias_once = (ksl == 0) ? bb[col] : 0.f;
            atomicAdd(op + col, w * (acc[mi][ni][r] + bias_once));
          }
        }
      }
    }
  }
}

// ---------------- kernels ----------------

// blocks [0,2048): zero out; [2048,2560): gate (4 tok/blk); [2560,6656): W1 transpose.
// cnt zeroed BEFORE via memset node (no intra-grid ordering). Transpose is now
// sched_barrier-fenced (see transpose_body) against the R3/R6 VGPR strangulation.
__global__ void __launch_bounds__(256) prep_kernel(
    const float* __restrict__ x, const float* __restrict__ Wg,
    const float* __restrict__ bg, const float* __restrict__ W1,
    float* __restrict__ out, int* __restrict__ cnt, int* __restrict__ btok,
    float* __restrict__ bw, unsigned short* __restrict__ W1t) {
  __shared__ __align__(16) char smem[17408];
  const int bid = blockIdx.x;
  if (bid < 2048) {
    ((float4*)out)[bid * 256 + threadIdx.x] = make_float4(0.f, 0.f, 0.f, 0.f);
  } else if (bid < 2560) {
    gate_body((bid - 2048) * 4 + (threadIdx.x >> 6), x, Wg, bg,
              out + (size_t)T_TOK * D_DIM, cnt, btok, bw);
  } else {
    const int lin = bid - 2560;          // 0..4095
    const int e = lin >> 9, l9 = lin & 511;
    // W1 [1024][2048] -> W1t [2048][1024]: out-stride 1024, 32 tx x 16 ty
    transpose_body(W1 + (size_t)e * (D_DIM * H_DIM), W1t + (size_t)e * (D_DIM * H_DIM),
                   D_DIM, H_DIM, l9 & 31, l9 >> 5, smem);
  }
}

// blocks [0,4096): moe_gemm<0> (A direct-gathered from x); [4096,8192): W2 transpose.
// W2t fusion proven in R3/R5 (combined 67us vs 63.6 bare gemm0): the gemm branch
// forces a healthy VGPR budget and the memory-bound transpose hides in gemm0's
// idle BW (~30%) and wave slots.
__global__ void __launch_bounds__(256) gemm0_w2t(
    const float* __restrict__ x, const unsigned short* __restrict__ W1t,
    const float* __restrict__ b1, const int* __restrict__ cnt,
    const int* __restrict__ btok, const float* __restrict__ bw,
    unsigned short* __restrict__ Hbuf, const float* __restrict__ W2,
    unsigned short* __restrict__ W2t) {
  __shared__ __align__(16) char smem[24576];
  if (blockIdx.x < 4096) {
    gemm_body<0>(blockIdx.x, x, nullptr, W1t, b1, cnt, btok, bw, Hbuf, nullptr, smem);
  } else {
    const int lin = blockIdx.x - 4096;   // 0..4095
    const int e = lin >> 9, l9 = lin & 511;
    // W2 [2048][1024] -> W2t [1024][2048]: out-stride 2048, 16 tx x 32 ty
    transpose_body(W2 + (size_t)e * (D_DIM * H_DIM), W2t + (size_t)e * (D_DIM * H_DIM),
                   H_DIM, D_DIM, l9 & 15, l9 >> 4, smem);
  }
}

__global__ void __launch_bounds__(256) moe_gemm1(
    const unsigned short* __restrict__ Hbuf, const unsigned short* __restrict__ W2t,
    const float* __restrict__ b2, const int* __restrict__ cnt,
    const int* __restrict__ btok, const float* __restrict__ bw,
    float* __restrict__ out) {
  __shared__ __align__(16) char smem[24576];
  gemm_body<1>(blockIdx.x, nullptr, Hbuf, W2t, b2, cnt, btok, bw, nullptr, out, smem);
}

extern "C" void kernel_launch(void* const* d_in, const int* in_sizes, int n_in,
                              void* d_out, int out_size, void* d_ws, size_t ws_size,
                              hipStream_t stream) {
  const float* moe_inp = (const float*)d_in[0];
  const float* Wg = (const float*)d_in[1];
  const float* bg = (const float*)d_in[2];
  const float* W1 = (const float*)d_in[3];
  const float* b1 = (const float*)d_in[4];
  const float* W2 = (const float*)d_in[5];
  const float* b2 = (const float*)d_in[6];
  float* out = (float*)d_out;

  char* ws = (char*)d_ws;
  int* cnt  = (int*)(ws + WS_CNT);
  int* btok = (int*)(ws + WS_BTOK);
  float* bw = (float*)(ws + WS_BW);
  unsigned short* Hbuf = (unsigned short*)(ws + WS_HBUF);
  unsigned short* W1t  = (unsigned short*)(ws + WS_W1T);
  unsigned short* W2t  = (unsigned short*)(ws + WS_W2T);

  hipMemsetAsync(cnt, 0, 256, stream);   // gate atomics need cnt=0 (capturable memset node)
  prep_kernel<<<dim3(6656), dim3(256), 0, stream>>>(moe_inp, Wg, bg, W1,
                                                    out, cnt, btok, bw, W1t);
  gemm0_w2t<<<dim3(8192), dim3(256), 0, stream>>>(moe_inp, W1t, b1, cnt, btok, bw,
                                                  Hbuf, W2, W2t);
  moe_gemm1<<<dim3(4096), dim3(256), 0, stream>>>(Hbuf, W2t, b2, cnt, btok, bw, out);
}